// Round 9
// baseline (566.299 us; speedup 1.0000x reference)
//
#include <hip/hip_runtime.h>

// ---------------------------------------------------------------------------
// BipartiteLayer: xp = x@W_in+b ; s = exp(-|[xp_i[s],xp_m[e]]@W_score+b|) ;
// scatter mean/max of xp_pair*s ; h = relu([x,xp,mean,max]@W_out+b)
//
// Pipeline:
//   k_prep_wt   : W (f32, KxN) -> Wt (N rows x K, bf16) transpose
//   k_gemm_in   : MFMA bf16 K=128 one-shot; fused bias, xp store, a=xp.Ws
//   k_deg/k_scan/k_fill : sorted CSR build (histogram -> prefix scan -> fill)
//                 replaces linked lists: gather iterations become INDEPENDENT
//                 (R8 lesson: dependent nxt[e] chains + barrier = latency hell)
//   k_agg_gemm  : FUSED per 16 nodes: streamed CSR gather -> H rows in LDS
//                 (swizzled), then 16x128 MFMA GEMM K=1408 vs Wt (L2-resident)
// ---------------------------------------------------------------------------

typedef __attribute__((ext_vector_type(8))) short bf16x8;   // 8 bf16 = 4 VGPR
typedef __attribute__((ext_vector_type(4))) float f32x4;

static __device__ __forceinline__ unsigned short f2bf(float f) {
  unsigned int u = __float_as_uint(f);
  u = (u + 0x7FFFu + ((u >> 16) & 1u)) >> 16;   // RNE
  return (unsigned short)u;
}
static __device__ __forceinline__ float bf2f(unsigned short s) {
  return __uint_as_float(((unsigned int)s) << 16);
}

#define GLD16(gp, lp)                                                        \
  __builtin_amdgcn_global_load_lds(                                          \
      (const __attribute__((address_space(1))) void*)(gp),                   \
      (__attribute__((address_space(3))) void*)(lp), 16, 0, 0)

// ---- transpose W (KxNcol f32) -> Wt[col][k] bf16 ---------------------------
__global__ void k_prep_wt(const float* __restrict__ Wo,
                          unsigned short* __restrict__ Wt, int K, int Ncol) {
  int idx = blockIdx.x * blockDim.x + threadIdx.x;
  if (idx >= K * Ncol) return;
  int k = idx / Ncol, c = idx % Ncol;
  Wt[(size_t)c * K + k] = f2bf(Wo[idx]);
}

// ---- input GEMM (MFMA): [N,128]f32 @ [128,256] -> xp bf16, a=xp.Ws --------
__global__ __launch_bounds__(256) void k_gemm_in(
    const float* __restrict__ x, const unsigned short* __restrict__ Wint,
    const float* __restrict__ bias, const float* __restrict__ Wsc,
    unsigned short* __restrict__ xp, float* __restrict__ a_out, int N) {
  __shared__ __align__(16) unsigned short Ab[64 * 16 * 8];    // 16 KB
  __shared__ __align__(16) unsigned short Bb[256 * 16 * 8];   // 64 KB
  const int tid = threadIdx.x;
  const int l = tid & 63;
  const int lr = l & 15, lg = l >> 4;
  const int w = tid >> 6, wr = w >> 1, wc = w & 1;
  const int r0 = blockIdx.x * 64;
  const int wbase = tid & 192;                  // w*64, wave-uniform

#pragma unroll
  for (int i = 0; i < 16; ++i) {                // B: 256 rows x 16 chunks
    int g = i * 256 + tid;
    int row = g >> 4, c = g & 15;
    int sc = c ^ (row & 7);
    GLD16(Wint + (size_t)row * 128 + sc * 8,
          &Bb[(size_t)(i * 256 + wbase) * 8]);
  }
#pragma unroll
  for (int i = 0; i < 4; ++i) {                 // A: reg-stage f32->bf16
    int g = i * 256 + tid;
    int row = g >> 4, c = g & 15;
    int ar = min(r0 + row, N - 1);
    const float* src = x + (size_t)ar * 128 + c * 8;
    float4 u = *(const float4*)src;
    float4 v = *(const float4*)(src + 4);
    bf16x8 h;
    h[0] = (short)f2bf(u.x); h[1] = (short)f2bf(u.y);
    h[2] = (short)f2bf(u.z); h[3] = (short)f2bf(u.w);
    h[4] = (short)f2bf(v.x); h[5] = (short)f2bf(v.y);
    h[6] = (short)f2bf(v.z); h[7] = (short)f2bf(v.w);
    *(bf16x8*)&Ab[(size_t)(row * 16 + (c ^ (row & 7))) * 8] = h;
  }
  __syncthreads();

  f32x4 acc[2][8];
#pragma unroll
  for (int m = 0; m < 2; ++m)
#pragma unroll
    for (int t = 0; t < 8; ++t) {
      f32x4 z = {0.f, 0.f, 0.f, 0.f};
      acc[m][t] = z;
    }
#pragma unroll
  for (int kk = 0; kk < 4; ++kk) {
    int chq = kk * 4 + lg;
    bf16x8 a[2], bt[8];
#pragma unroll
    for (int m = 0; m < 2; ++m) {
      int row = wr * 32 + m * 16 + lr;
      a[m] = *(const bf16x8*)&Ab[(row * 16 + (chq ^ (row & 7))) * 8];
    }
#pragma unroll
    for (int t = 0; t < 8; ++t) {
      int row = wc * 128 + t * 16 + lr;
      bt[t] = *(const bf16x8*)&Bb[(row * 16 + (chq ^ (row & 7))) * 8];
    }
#pragma unroll
    for (int m = 0; m < 2; ++m)
#pragma unroll
      for (int t = 0; t < 8; ++t)
        acc[m][t] = __builtin_amdgcn_mfma_f32_16x16x32_bf16(
            a[m], bt[t], acc[m][t], 0, 0, 0);
  }

  float wscv[8], bb[8];
#pragma unroll
  for (int t = 0; t < 8; ++t) {
    int c = wc * 128 + t * 16 + lr;
    wscv[t] = Wsc[c];
    bb[t] = bias[c];
  }
#pragma unroll
  for (int m = 0; m < 2; ++m) {
    int rb = r0 + wr * 32 + m * 16 + lg * 4;    // C/D: col=lane&15, row=lg*4+reg
    float p0 = 0.f, p1 = 0.f, p2 = 0.f, p3 = 0.f;
#pragma unroll
    for (int t = 0; t < 8; ++t) {
      int c = wc * 128 + t * 16 + lr;
      float v0 = acc[m][t][0] + bb[t];
      float v1 = acc[m][t][1] + bb[t];
      float v2 = acc[m][t][2] + bb[t];
      float v3 = acc[m][t][3] + bb[t];
      if (rb + 0 < N) xp[(size_t)(rb + 0) * 256 + c] = f2bf(v0);
      if (rb + 1 < N) xp[(size_t)(rb + 1) * 256 + c] = f2bf(v1);
      if (rb + 2 < N) xp[(size_t)(rb + 2) * 256 + c] = f2bf(v2);
      if (rb + 3 < N) xp[(size_t)(rb + 3) * 256 + c] = f2bf(v3);
      p0 = fmaf(v0, wscv[t], p0); p1 = fmaf(v1, wscv[t], p1);
      p2 = fmaf(v2, wscv[t], p2); p3 = fmaf(v3, wscv[t], p3);
    }
#pragma unroll
    for (int off = 1; off < 16; off <<= 1) {
      p0 += __shfl_xor(p0, off); p1 += __shfl_xor(p1, off);
      p2 += __shfl_xor(p2, off); p3 += __shfl_xor(p3, off);
    }
    if (lr == 0) {
      if (rb + 0 < N) atomicAdd(a_out + rb + 0, p0);
      if (rb + 1 < N) atomicAdd(a_out + rb + 1, p1);
      if (rb + 2 < N) atomicAdd(a_out + rb + 2, p2);
      if (rb + 3 < N) atomicAdd(a_out + rb + 3, p3);
    }
  }
}

// ---- CSR build: degree histogram ------------------------------------------
__global__ void k_deg(const int* __restrict__ es, const int* __restrict__ ee,
                      int E, int* __restrict__ deg_i, int* __restrict__ deg_m) {
  int e = blockIdx.x * blockDim.x + threadIdx.x;
  if (e >= E) return;
  atomicAdd(deg_i + es[e], 1);
  atomicAdd(deg_m + ee[e], 1);
}

// ---- CSR build: exclusive prefix scan (1 block per side) ------------------
__global__ __launch_bounds__(1024) void k_scan(
    const int* __restrict__ deg_i, int* __restrict__ rp_i, int* __restrict__ cur_i,
    const int* __restrict__ deg_m, int* __restrict__ rp_m, int* __restrict__ cur_m,
    int Ni, int Nm) {
  const int* deg = blockIdx.x ? deg_m : deg_i;
  int* rp = blockIdx.x ? rp_m : rp_i;
  int* cur = blockIdx.x ? cur_m : cur_i;
  int n = blockIdx.x ? Nm : Ni;
  __shared__ int part[1024];
  int t = threadIdx.x;
  int chunk = (n + 1023) >> 10;
  int b0 = t * chunk;
  int e0 = min(b0 + chunk, n);
  int s = 0;
  for (int i = b0; i < e0; ++i) s += deg[i];
  part[t] = s;
  __syncthreads();
  for (int off = 1; off < 1024; off <<= 1) {    // Hillis-Steele inclusive
    int v = (t >= off) ? part[t - off] : 0;
    __syncthreads();
    part[t] += v;
    __syncthreads();
  }
  int run = (t > 0) ? part[t - 1] : 0;          // exclusive prefix of chunk
  for (int i = b0; i < e0; ++i) {
    rp[i] = run; cur[i] = run;
    run += deg[i];
  }
  if (e0 == n) rp[n] = run;                     // total (= E)
}

// ---- CSR build: score + fill ----------------------------------------------
__global__ void k_fill(const int* __restrict__ es, const int* __restrict__ ee,
                       int E, const float* __restrict__ a_i,
                       const float* __restrict__ a_m,
                       const float* __restrict__ bsc,
                       int* __restrict__ cur_i, int* __restrict__ col_i,
                       float* __restrict__ sv_i,
                       int* __restrict__ cur_m, int* __restrict__ col_m,
                       float* __restrict__ sv_m) {
  int e = blockIdx.x * blockDim.x + threadIdx.x;
  if (e >= E) return;
  int s = es[e], m = ee[e];
  float sc = expf(-fabsf(a_i[s] + a_m[m] + bsc[0]));
  int pi = atomicAdd(cur_i + s, 1);
  col_i[pi] = m; sv_i[pi] = sc;
  int pm = atomicAdd(cur_m + m, 1);
  col_m[pm] = s; sv_m[pm] = sc;
}

// ---- FUSED agg + output GEMM ----------------------------------------------
// Block: 512 thr / 8 waves; 16 nodes per block. CSR gather (independent
// iterations, 2x unrolled) -> H rows in LDS (swizzled chunk^row&7), barrier,
// then 16x128 MFMA K=1408 (A from LDS, B = Wt rows from L2), bias+relu.
// H = [x(128) | xp(256) | mean(512) | max(512)]
__global__ __launch_bounds__(512) void k_agg_gemm(
    const float* __restrict__ x_own, const unsigned short* __restrict__ xp_own,
    const unsigned short* __restrict__ xp_oth,
    const int* __restrict__ rowptr, const int* __restrict__ col,
    const float* __restrict__ sv, const unsigned short* __restrict__ Wt,
    const float* __restrict__ bias, float* __restrict__ out,
    int N, int own_off, int oth_off) {
  __shared__ __align__(16) unsigned short Hs[16 * 1408];   // 44 KB
  const int tid = threadIdx.x;
  const int l = tid & 63;
  const int wv = tid >> 6;                      // 0..7
  const int base = blockIdx.x * 16;

  auto st4 = [&](int row, int colm, ushort4 v) {
    int ch = colm >> 3, wi = colm & 7;
    *(ushort4*)&Hs[(size_t)row * 1408 + ((ch ^ (row & 7)) << 3) + wi] = v;
  };
  auto st2 = [&](int row, int colm, ushort2 v) {
    int ch = colm >> 3, wi = colm & 7;
    *(ushort2*)&Hs[(size_t)row * 1408 + ((ch ^ (row & 7)) << 3) + wi] = v;
  };

  // ---- phase 1: build 16 H rows (2 nodes per wave) ----
  for (int rr = wv; rr < 16; rr += 8) {
    int node = base + rr;
    if (node >= N) node = N - 1;                // duplicate row; store-guarded
    ushort4 xo = *(const ushort4*)(xp_own + (size_t)node * 256 + 4 * l);
    float xp0 = bf2f(xo.x), xp1 = bf2f(xo.y), xp2 = bf2f(xo.z), xp3 = bf2f(xo.w);
    float2 xv = *(const float2*)(x_own + (size_t)node * 128 + 2 * l);
    st2(rr, 2 * l, make_ushort2(f2bf(xv.x), f2bf(xv.y)));
    st4(rr, 128 + 4 * l, xo);

    float sum_s = 0.f, mx_s = -1e30f, mn_s = 1e30f;
    float sv0 = 0.f, sv1 = 0.f, sv2 = 0.f, sv3 = 0.f;
    float mv0 = -1e30f, mv1 = -1e30f, mv2 = -1e30f, mv3 = -1e30f;
    int jb = rowptr[node], je = rowptr[node + 1];
    int dg = je - jb;
    int j = jb;
    for (; j + 1 < je; j += 2) {                // independent, 2 in flight
      int o0 = col[j], o1 = col[j + 1];
      float s0 = sv[j], s1 = sv[j + 1];
      ushort4 g0 = *(const ushort4*)(xp_oth + (size_t)o0 * 256 + 4 * l);
      ushort4 g1 = *(const ushort4*)(xp_oth + (size_t)o1 * 256 + 4 * l);
      float f0 = bf2f(g0.x), f1 = bf2f(g0.y), f2 = bf2f(g0.z), f3 = bf2f(g0.w);
      sv0 = fmaf(s0, f0, sv0); sv1 = fmaf(s0, f1, sv1);
      sv2 = fmaf(s0, f2, sv2); sv3 = fmaf(s0, f3, sv3);
      mv0 = fmaxf(mv0, s0 * f0); mv1 = fmaxf(mv1, s0 * f1);
      mv2 = fmaxf(mv2, s0 * f2); mv3 = fmaxf(mv3, s0 * f3);
      float h0 = bf2f(g1.x), h1 = bf2f(g1.y), h2 = bf2f(g1.z), h3 = bf2f(g1.w);
      sv0 = fmaf(s1, h0, sv0); sv1 = fmaf(s1, h1, sv1);
      sv2 = fmaf(s1, h2, sv2); sv3 = fmaf(s1, h3, sv3);
      mv0 = fmaxf(mv0, s1 * h0); mv1 = fmaxf(mv1, s1 * h1);
      mv2 = fmaxf(mv2, s1 * h2); mv3 = fmaxf(mv3, s1 * h3);
      sum_s += s0 + s1;
      mx_s = fmaxf(mx_s, fmaxf(s0, s1)); mn_s = fminf(mn_s, fminf(s0, s1));
    }
    if (j < je) {
      int o0 = col[j];
      float s0 = sv[j];
      ushort4 g0 = *(const ushort4*)(xp_oth + (size_t)o0 * 256 + 4 * l);
      float f0 = bf2f(g0.x), f1 = bf2f(g0.y), f2 = bf2f(g0.z), f3 = bf2f(g0.w);
      sv0 = fmaf(s0, f0, sv0); sv1 = fmaf(s0, f1, sv1);
      sv2 = fmaf(s0, f2, sv2); sv3 = fmaf(s0, f3, sv3);
      mv0 = fmaxf(mv0, s0 * f0); mv1 = fmaxf(mv1, s0 * f1);
      mv2 = fmaxf(mv2, s0 * f2); mv3 = fmaxf(mv3, s0 * f3);
      sum_s += s0; mx_s = fmaxf(mx_s, s0); mn_s = fminf(mn_s, s0);
    }
    float inv = 1.f / (float)(dg > 0 ? dg : 1);
    float ss = sum_s * inv;
    st4(rr, 384 + own_off + 4 * l, make_ushort4(
        f2bf(xp0 * ss), f2bf(xp1 * ss), f2bf(xp2 * ss), f2bf(xp3 * ss)));
    st4(rr, 384 + oth_off + 4 * l, make_ushort4(
        f2bf(sv0 * inv), f2bf(sv1 * inv), f2bf(sv2 * inv), f2bf(sv3 * inv)));
    float a0, a1, a2, a3;
    if (dg > 0) {
      a0 = fmaxf(fmaxf(xp0 * mx_s, xp0 * mn_s), 0.f);
      a1 = fmaxf(fmaxf(xp1 * mx_s, xp1 * mn_s), 0.f);
      a2 = fmaxf(fmaxf(xp2 * mx_s, xp2 * mn_s), 0.f);
      a3 = fmaxf(fmaxf(xp3 * mx_s, xp3 * mn_s), 0.f);
    } else {
      a0 = a1 = a2 = a3 = 0.f;
    }
    st4(rr, 896 + own_off + 4 * l, make_ushort4(f2bf(a0), f2bf(a1),
                                                f2bf(a2), f2bf(a3)));
    st4(rr, 896 + oth_off + 4 * l, make_ushort4(
        f2bf(fmaxf(mv0, 0.f)), f2bf(fmaxf(mv1, 0.f)),
        f2bf(fmaxf(mv2, 0.f)), f2bf(fmaxf(mv3, 0.f))));
  }
  __syncthreads();

  // ---- phase 2: out[16 rows][128 cols] = H @ Wt^T + b, relu ----
  const int lr = l & 15, lg = l >> 4;
  const int c = wv * 16 + lr;
  const unsigned short* Wr = Wt + (size_t)c * 1408;
  f32x4 acc = {0.f, 0.f, 0.f, 0.f};
#pragma unroll 8
  for (int kc = 0; kc < 44; ++kc) {
    bf16x8 a = *(const bf16x8*)&Hs[(size_t)lr * 1408 +
                                   (((kc * 4 + lg) ^ (lr & 7)) << 3)];
    bf16x8 b = *(const bf16x8*)(Wr + kc * 32 + lg * 8);
    acc = __builtin_amdgcn_mfma_f32_16x16x32_bf16(a, b, acc, 0, 0, 0);
  }
  float bb = bias[c];
#pragma unroll
  for (int jj = 0; jj < 4; ++jj) {              // C/D: col=lane&15, row=lg*4+j
    int row = base + lg * 4 + jj;
    if (row < N) out[(size_t)row * 128 + c] = fmaxf(acc[jj] + bb, 0.f);
  }
}

extern "C" void kernel_launch(void* const* d_in, const int* in_sizes, int n_in,
                              void* d_out, int out_size, void* d_ws,
                              size_t ws_size, hipStream_t stream) {
  const float* x_i  = (const float*)d_in[0];
  const float* x_m  = (const float*)d_in[1];
  const int*   ei   = (const int*)d_in[2];
  const float* Wi_i = (const float*)d_in[3];
  const float* bi_i = (const float*)d_in[4];
  const float* Wi_m = (const float*)d_in[5];
  const float* bi_m = (const float*)d_in[6];
  const float* Wsc  = (const float*)d_in[7];
  const float* bsc  = (const float*)d_in[8];
  const float* Wo_i = (const float*)d_in[9];
  const float* bo_i = (const float*)d_in[10];
  const float* Wo_m = (const float*)d_in[11];
  const float* bo_m = (const float*)d_in[12];
  float* out = (float*)d_out;

  int Ni = in_sizes[0] / 128, Nm = in_sizes[1] / 128, E = in_sizes[2] / 2;
  const int* es = ei;
  const int* ee = ei + E;

  char* p = (char*)d_ws;
  auto alloc = [&](size_t bytes) {
    char* q = p;
    p += (bytes + 255) & ~(size_t)255;
    return q;
  };
  unsigned short* xp_i = (unsigned short*)alloc((size_t)Ni * 256 * 2);
  unsigned short* xp_m = (unsigned short*)alloc((size_t)Nm * 256 * 2);
  float* a_i   = (float*)alloc((size_t)Ni * 4);
  float* a_m   = (float*)alloc((size_t)Nm * 4);
  int* deg_i   = (int*)alloc((size_t)Ni * 4);
  int* deg_m   = (int*)alloc((size_t)Nm * 4);
  int* rp_i    = (int*)alloc((size_t)(Ni + 1) * 4);
  int* rp_m    = (int*)alloc((size_t)(Nm + 1) * 4);
  int* cur_i   = (int*)alloc((size_t)Ni * 4);
  int* cur_m   = (int*)alloc((size_t)Nm * 4);
  int* col_i   = (int*)alloc((size_t)E * 4);
  int* col_m   = (int*)alloc((size_t)E * 4);
  float* sv_i  = (float*)alloc((size_t)E * 4);
  float* sv_m  = (float*)alloc((size_t)E * 4);
  unsigned short* Wt_i = (unsigned short*)alloc((size_t)128 * 1408 * 2);
  unsigned short* Wt_m = (unsigned short*)alloc((size_t)128 * 1408 * 2);
  unsigned short* Wint_i = (unsigned short*)alloc((size_t)256 * 128 * 2);
  unsigned short* Wint_m = (unsigned short*)alloc((size_t)256 * 128 * 2);
  if ((size_t)(p - (char*)d_ws) > ws_size) return;   // ~59 MB fixed scratch

  hipMemsetAsync(deg_i, 0, (size_t)Ni * 4, stream);
  hipMemsetAsync(deg_m, 0, (size_t)Nm * 4, stream);
  hipMemsetAsync(a_i, 0, (size_t)Ni * 4, stream);
  hipMemsetAsync(a_m, 0, (size_t)Nm * 4, stream);

  k_prep_wt<<<(1408 * 128 + 255) / 256, 256, 0, stream>>>(Wo_i, Wt_i, 1408, 128);
  k_prep_wt<<<(1408 * 128 + 255) / 256, 256, 0, stream>>>(Wo_m, Wt_m, 1408, 128);
  k_prep_wt<<<(128 * 256 + 255) / 256, 256, 0, stream>>>(Wi_i, Wint_i, 128, 256);
  k_prep_wt<<<(128 * 256 + 255) / 256, 256, 0, stream>>>(Wi_m, Wint_m, 128, 256);

  k_gemm_in<<<(Ni + 63) / 64, 256, 0, stream>>>(x_i, Wint_i, bi_i, Wsc, xp_i, a_i, Ni);
  k_gemm_in<<<(Nm + 63) / 64, 256, 0, stream>>>(x_m, Wint_m, bi_m, Wsc + 256, xp_m, a_m, Nm);

  k_deg<<<(E + 255) / 256, 256, 0, stream>>>(es, ee, E, deg_i, deg_m);
  k_scan<<<2, 1024, 0, stream>>>(deg_i, rp_i, cur_i, deg_m, rp_m, cur_m, Ni, Nm);
  k_fill<<<(E + 255) / 256, 256, 0, stream>>>(es, ee, E, a_i, a_m, bsc,
                                              cur_i, col_i, sv_i,
                                              cur_m, col_m, sv_m);

  // intt side: own half of pooled cols at [0,256), gathered (mvtx) at [256,512)
  k_agg_gemm<<<(Ni + 15) / 16, 512, 0, stream>>>(
      x_i, xp_i, xp_m, rp_i, col_i, sv_i, Wt_i, bo_i, out, Ni, 0, 256);
  // mvtx side: gathered (intt) at [0,256), own half at [256,512)
  k_agg_gemm<<<(Nm + 15) / 16, 512, 0, stream>>>(
      x_m, xp_m, xp_i, rp_m, col_m, sv_m, Wt_m, bo_m,
      out + (size_t)Ni * 128, Nm, 256, 0);
}

// Round 10
// 440.449 us; speedup vs baseline: 1.2857x; 1.2857x over previous
//
#include <hip/hip_runtime.h>

// ---------------------------------------------------------------------------
// BipartiteLayer: xp = x@W_in+b ; s = exp(-|[xp_i[s],xp_m[e]]@W_score+b|) ;
// scatter mean/max of xp_pair*s ; h = relu([x,xp,mean,max]@W_out+b)
//
// R10: revert to the PROVEN split pipeline (R7, 344 us) — fusion abandoned
// (R8/R9: M=16-per-block GEMM has 16x worse Wt reuse + barrier tail).
// One change vs R7: linked-list gather -> sorted CSR + 4-wide unroll
// (4 independent 512B gathers in flight per wave vs 1 for the list walk).
//
// Pipeline (slab-chunked H to fit adaptive workspace):
//   k_prep_wt     : W (f32, KxN) -> Wt (N rows x K, bf16) transpose
//   k_gemm_in     : MFMA bf16 K=128 one-shot; fused bias, xp store, a=xp.Ws
//   k_deg/scan/fill: sorted CSR build (R9-proven)
//   per slab:
//     k_agg       : wave-per-node CSR gather-reduce -> H slab rows (1408 bf16)
//     k_gemm_out  : bf16 MFMA, 64x128 tile, BK=64 dbuf LDS via global_load_lds
// ---------------------------------------------------------------------------

typedef __attribute__((ext_vector_type(8))) short bf16x8;   // 8 bf16 = 4 VGPR
typedef __attribute__((ext_vector_type(4))) float f32x4;

static __device__ __forceinline__ unsigned short f2bf(float f) {
  unsigned int u = __float_as_uint(f);
  u = (u + 0x7FFFu + ((u >> 16) & 1u)) >> 16;   // RNE
  return (unsigned short)u;
}
static __device__ __forceinline__ float bf2f(unsigned short s) {
  return __uint_as_float(((unsigned int)s) << 16);
}

#define GLD16(gp, lp)                                                        \
  __builtin_amdgcn_global_load_lds(                                          \
      (const __attribute__((address_space(1))) void*)(gp),                   \
      (__attribute__((address_space(3))) void*)(lp), 16, 0, 0)

// ---- transpose W (KxNcol f32) -> Wt[col][k] bf16 ---------------------------
__global__ void k_prep_wt(const float* __restrict__ Wo,
                          unsigned short* __restrict__ Wt, int K, int Ncol) {
  int idx = blockIdx.x * blockDim.x + threadIdx.x;
  if (idx >= K * Ncol) return;
  int k = idx / Ncol, c = idx % Ncol;
  Wt[(size_t)c * K + k] = f2bf(Wo[idx]);
}

// ---- input GEMM (MFMA): [N,128]f32 @ [128,256] -> xp bf16, a=xp.Ws --------
__global__ __launch_bounds__(256) void k_gemm_in(
    const float* __restrict__ x, const unsigned short* __restrict__ Wint,
    const float* __restrict__ bias, const float* __restrict__ Wsc,
    unsigned short* __restrict__ xp, float* __restrict__ a_out, int N) {
  __shared__ __align__(16) unsigned short Ab[64 * 16 * 8];    // 16 KB
  __shared__ __align__(16) unsigned short Bb[256 * 16 * 8];   // 64 KB
  const int tid = threadIdx.x;
  const int l = tid & 63;
  const int lr = l & 15, lg = l >> 4;
  const int w = tid >> 6, wr = w >> 1, wc = w & 1;
  const int r0 = blockIdx.x * 64;
  const int wbase = tid & 192;                  // w*64, wave-uniform

#pragma unroll
  for (int i = 0; i < 16; ++i) {                // B: 256 rows x 16 chunks
    int g = i * 256 + tid;
    int row = g >> 4, c = g & 15;
    int sc = c ^ (row & 7);
    GLD16(Wint + (size_t)row * 128 + sc * 8,
          &Bb[(size_t)(i * 256 + wbase) * 8]);
  }
#pragma unroll
  for (int i = 0; i < 4; ++i) {                 // A: reg-stage f32->bf16
    int g = i * 256 + tid;
    int row = g >> 4, c = g & 15;
    int ar = min(r0 + row, N - 1);
    const float* src = x + (size_t)ar * 128 + c * 8;
    float4 u = *(const float4*)src;
    float4 v = *(const float4*)(src + 4);
    bf16x8 h;
    h[0] = (short)f2bf(u.x); h[1] = (short)f2bf(u.y);
    h[2] = (short)f2bf(u.z); h[3] = (short)f2bf(u.w);
    h[4] = (short)f2bf(v.x); h[5] = (short)f2bf(v.y);
    h[6] = (short)f2bf(v.z); h[7] = (short)f2bf(v.w);
    *(bf16x8*)&Ab[(size_t)(row * 16 + (c ^ (row & 7))) * 8] = h;
  }
  __syncthreads();

  f32x4 acc[2][8];
#pragma unroll
  for (int m = 0; m < 2; ++m)
#pragma unroll
    for (int t = 0; t < 8; ++t) {
      f32x4 z = {0.f, 0.f, 0.f, 0.f};
      acc[m][t] = z;
    }
#pragma unroll
  for (int kk = 0; kk < 4; ++kk) {
    int chq = kk * 4 + lg;
    bf16x8 a[2], bt[8];
#pragma unroll
    for (int m = 0; m < 2; ++m) {
      int row = wr * 32 + m * 16 + lr;
      a[m] = *(const bf16x8*)&Ab[(row * 16 + (chq ^ (row & 7))) * 8];
    }
#pragma unroll
    for (int t = 0; t < 8; ++t) {
      int row = wc * 128 + t * 16 + lr;
      bt[t] = *(const bf16x8*)&Bb[(row * 16 + (chq ^ (row & 7))) * 8];
    }
#pragma unroll
    for (int m = 0; m < 2; ++m)
#pragma unroll
      for (int t = 0; t < 8; ++t)
        acc[m][t] = __builtin_amdgcn_mfma_f32_16x16x32_bf16(
            a[m], bt[t], acc[m][t], 0, 0, 0);
  }

  float wscv[8], bb[8];
#pragma unroll
  for (int t = 0; t < 8; ++t) {
    int c = wc * 128 + t * 16 + lr;
    wscv[t] = Wsc[c];
    bb[t] = bias[c];
  }
#pragma unroll
  for (int m = 0; m < 2; ++m) {
    int rb = r0 + wr * 32 + m * 16 + lg * 4;    // C/D: col=lane&15, row=lg*4+reg
    float p0 = 0.f, p1 = 0.f, p2 = 0.f, p3 = 0.f;
#pragma unroll
    for (int t = 0; t < 8; ++t) {
      int c = wc * 128 + t * 16 + lr;
      float v0 = acc[m][t][0] + bb[t];
      float v1 = acc[m][t][1] + bb[t];
      float v2 = acc[m][t][2] + bb[t];
      float v3 = acc[m][t][3] + bb[t];
      if (rb + 0 < N) xp[(size_t)(rb + 0) * 256 + c] = f2bf(v0);
      if (rb + 1 < N) xp[(size_t)(rb + 1) * 256 + c] = f2bf(v1);
      if (rb + 2 < N) xp[(size_t)(rb + 2) * 256 + c] = f2bf(v2);
      if (rb + 3 < N) xp[(size_t)(rb + 3) * 256 + c] = f2bf(v3);
      p0 = fmaf(v0, wscv[t], p0); p1 = fmaf(v1, wscv[t], p1);
      p2 = fmaf(v2, wscv[t], p2); p3 = fmaf(v3, wscv[t], p3);
    }
#pragma unroll
    for (int off = 1; off < 16; off <<= 1) {
      p0 += __shfl_xor(p0, off); p1 += __shfl_xor(p1, off);
      p2 += __shfl_xor(p2, off); p3 += __shfl_xor(p3, off);
    }
    if (lr == 0) {
      if (rb + 0 < N) atomicAdd(a_out + rb + 0, p0);
      if (rb + 1 < N) atomicAdd(a_out + rb + 1, p1);
      if (rb + 2 < N) atomicAdd(a_out + rb + 2, p2);
      if (rb + 3 < N) atomicAdd(a_out + rb + 3, p3);
    }
  }
}

// ---- CSR build: degree histogram ------------------------------------------
__global__ void k_deg(const int* __restrict__ es, const int* __restrict__ ee,
                      int E, int* __restrict__ deg_i, int* __restrict__ deg_m) {
  int e = blockIdx.x * blockDim.x + threadIdx.x;
  if (e >= E) return;
  atomicAdd(deg_i + es[e], 1);
  atomicAdd(deg_m + ee[e], 1);
}

// ---- CSR build: exclusive prefix scan (1 block per side) ------------------
__global__ __launch_bounds__(1024) void k_scan(
    const int* __restrict__ deg_i, int* __restrict__ rp_i, int* __restrict__ cur_i,
    const int* __restrict__ deg_m, int* __restrict__ rp_m, int* __restrict__ cur_m,
    int Ni, int Nm) {
  const int* deg = blockIdx.x ? deg_m : deg_i;
  int* rp = blockIdx.x ? rp_m : rp_i;
  int* cur = blockIdx.x ? cur_m : cur_i;
  int n = blockIdx.x ? Nm : Ni;
  __shared__ int part[1024];
  int t = threadIdx.x;
  int chunk = (n + 1023) >> 10;
  int b0 = t * chunk;
  int e0 = min(b0 + chunk, n);
  int s = 0;
  for (int i = b0; i < e0; ++i) s += deg[i];
  part[t] = s;
  __syncthreads();
  for (int off = 1; off < 1024; off <<= 1) {    // Hillis-Steele inclusive
    int v = (t >= off) ? part[t - off] : 0;
    __syncthreads();
    part[t] += v;
    __syncthreads();
  }
  int run = (t > 0) ? part[t - 1] : 0;          // exclusive prefix of chunk
  for (int i = b0; i < e0; ++i) {
    rp[i] = run; cur[i] = run;
    run += deg[i];
  }
  if (e0 == n) rp[n] = run;                     // total (= E)
}

// ---- CSR build: score + fill ----------------------------------------------
__global__ void k_fill(const int* __restrict__ es, const int* __restrict__ ee,
                       int E, const float* __restrict__ a_i,
                       const float* __restrict__ a_m,
                       const float* __restrict__ bsc,
                       int* __restrict__ cur_i, int* __restrict__ col_i,
                       float* __restrict__ sv_i,
                       int* __restrict__ cur_m, int* __restrict__ col_m,
                       float* __restrict__ sv_m) {
  int e = blockIdx.x * blockDim.x + threadIdx.x;
  if (e >= E) return;
  int s = es[e], m = ee[e];
  float sc = expf(-fabsf(a_i[s] + a_m[m] + bsc[0]));
  int pi = atomicAdd(cur_i + s, 1);
  col_i[pi] = m; sv_i[pi] = sc;
  int pm = atomicAdd(cur_m + m, 1);
  col_m[pm] = s; sv_m[pm] = sc;
}

// ---- wave-per-node CSR aggregation -> H slab row (1408 bf16) ---------------
// H = [x(128) | xp(256) | mean(512) | max(512)]; 4 gathers in flight.
__global__ __launch_bounds__(256) void k_agg(
    const float* __restrict__ x_own, const unsigned short* __restrict__ xp_own,
    const unsigned short* __restrict__ xp_oth,
    const int* __restrict__ rowptr, const int* __restrict__ col,
    const float* __restrict__ sv, unsigned short* __restrict__ H,
    int base, int cnt, int own_off, int oth_off) {
  int local = blockIdx.x * 4 + (threadIdx.x >> 6);
  if (local >= cnt) return;                      // wave-uniform
  int node = base + local;
  int l = threadIdx.x & 63;
  ushort4 xo = *(const ushort4*)(xp_own + (size_t)node * 256 + 4 * l);
  float xp0 = bf2f(xo.x), xp1 = bf2f(xo.y), xp2 = bf2f(xo.z), xp3 = bf2f(xo.w);
  float2 xv = *(const float2*)(x_own + (size_t)node * 128 + 2 * l);
  unsigned short* Hr = H + (size_t)local * 1408;
  *(ushort2*)(Hr + 2 * l) = make_ushort2(f2bf(xv.x), f2bf(xv.y));
  *(ushort4*)(Hr + 128 + 4 * l) = xo;

  float sum_s = 0.f, mx_s = -1e30f, mn_s = 1e30f;
  float sv0 = 0.f, sv1 = 0.f, sv2 = 0.f, sv3 = 0.f;
  float mv0 = -1e30f, mv1 = -1e30f, mv2 = -1e30f, mv3 = -1e30f;
  int jb = rowptr[node], je = rowptr[node + 1];
  int dg = je - jb;
  int j = jb;
  for (; j + 3 < je; j += 4) {                   // 4 independent gathers
    int o0 = col[j], o1 = col[j + 1], o2 = col[j + 2], o3 = col[j + 3];
    float s0 = sv[j], s1 = sv[j + 1], s2 = sv[j + 2], s3 = sv[j + 3];
    ushort4 g0 = *(const ushort4*)(xp_oth + (size_t)o0 * 256 + 4 * l);
    ushort4 g1 = *(const ushort4*)(xp_oth + (size_t)o1 * 256 + 4 * l);
    ushort4 g2 = *(const ushort4*)(xp_oth + (size_t)o2 * 256 + 4 * l);
    ushort4 g3 = *(const ushort4*)(xp_oth + (size_t)o3 * 256 + 4 * l);
    float f0, f1, f2, f3;
    f0 = bf2f(g0.x); f1 = bf2f(g0.y); f2 = bf2f(g0.z); f3 = bf2f(g0.w);
    sv0 = fmaf(s0, f0, sv0); sv1 = fmaf(s0, f1, sv1);
    sv2 = fmaf(s0, f2, sv2); sv3 = fmaf(s0, f3, sv3);
    mv0 = fmaxf(mv0, s0 * f0); mv1 = fmaxf(mv1, s0 * f1);
    mv2 = fmaxf(mv2, s0 * f2); mv3 = fmaxf(mv3, s0 * f3);
    f0 = bf2f(g1.x); f1 = bf2f(g1.y); f2 = bf2f(g1.z); f3 = bf2f(g1.w);
    sv0 = fmaf(s1, f0, sv0); sv1 = fmaf(s1, f1, sv1);
    sv2 = fmaf(s1, f2, sv2); sv3 = fmaf(s1, f3, sv3);
    mv0 = fmaxf(mv0, s1 * f0); mv1 = fmaxf(mv1, s1 * f1);
    mv2 = fmaxf(mv2, s1 * f2); mv3 = fmaxf(mv3, s1 * f3);
    f0 = bf2f(g2.x); f1 = bf2f(g2.y); f2 = bf2f(g2.z); f3 = bf2f(g2.w);
    sv0 = fmaf(s2, f0, sv0); sv1 = fmaf(s2, f1, sv1);
    sv2 = fmaf(s2, f2, sv2); sv3 = fmaf(s2, f3, sv3);
    mv0 = fmaxf(mv0, s2 * f0); mv1 = fmaxf(mv1, s2 * f1);
    mv2 = fmaxf(mv2, s2 * f2); mv3 = fmaxf(mv3, s2 * f3);
    f0 = bf2f(g3.x); f1 = bf2f(g3.y); f2 = bf2f(g3.z); f3 = bf2f(g3.w);
    sv0 = fmaf(s3, f0, sv0); sv1 = fmaf(s3, f1, sv1);
    sv2 = fmaf(s3, f2, sv2); sv3 = fmaf(s3, f3, sv3);
    mv0 = fmaxf(mv0, s3 * f0); mv1 = fmaxf(mv1, s3 * f1);
    mv2 = fmaxf(mv2, s3 * f2); mv3 = fmaxf(mv3, s3 * f3);
    sum_s += (s0 + s1) + (s2 + s3);
    mx_s = fmaxf(mx_s, fmaxf(fmaxf(s0, s1), fmaxf(s2, s3)));
    mn_s = fminf(mn_s, fminf(fminf(s0, s1), fminf(s2, s3)));
  }
  for (; j < je; ++j) {                          // tail 0..3
    int o0 = col[j];
    float s0 = sv[j];
    ushort4 g0 = *(const ushort4*)(xp_oth + (size_t)o0 * 256 + 4 * l);
    float f0 = bf2f(g0.x), f1 = bf2f(g0.y), f2 = bf2f(g0.z), f3 = bf2f(g0.w);
    sv0 = fmaf(s0, f0, sv0); sv1 = fmaf(s0, f1, sv1);
    sv2 = fmaf(s0, f2, sv2); sv3 = fmaf(s0, f3, sv3);
    mv0 = fmaxf(mv0, s0 * f0); mv1 = fmaxf(mv1, s0 * f1);
    mv2 = fmaxf(mv2, s0 * f2); mv3 = fmaxf(mv3, s0 * f3);
    sum_s += s0; mx_s = fmaxf(mx_s, s0); mn_s = fminf(mn_s, s0);
  }
  float inv = 1.f / (float)(dg > 0 ? dg : 1);
  float ss = sum_s * inv;
  *(ushort4*)(Hr + 384 + own_off + 4 * l) = make_ushort4(
      f2bf(xp0 * ss), f2bf(xp1 * ss), f2bf(xp2 * ss), f2bf(xp3 * ss));
  *(ushort4*)(Hr + 384 + oth_off + 4 * l) = make_ushort4(
      f2bf(sv0 * inv), f2bf(sv1 * inv), f2bf(sv2 * inv), f2bf(sv3 * inv));
  float a0, a1, a2, a3;
  if (dg > 0) {
    a0 = fmaxf(fmaxf(xp0 * mx_s, xp0 * mn_s), 0.f);
    a1 = fmaxf(fmaxf(xp1 * mx_s, xp1 * mn_s), 0.f);
    a2 = fmaxf(fmaxf(xp2 * mx_s, xp2 * mn_s), 0.f);
    a3 = fmaxf(fmaxf(xp3 * mx_s, xp3 * mn_s), 0.f);
  } else {
    a0 = a1 = a2 = a3 = 0.f;
  }
  *(ushort4*)(Hr + 896 + own_off + 4 * l) =
      make_ushort4(f2bf(a0), f2bf(a1), f2bf(a2), f2bf(a3));
  *(ushort4*)(Hr + 896 + oth_off + 4 * l) =
      make_ushort4(f2bf(fmaxf(mv0, 0.f)), f2bf(fmaxf(mv1, 0.f)),
                   f2bf(fmaxf(mv2, 0.f)), f2bf(fmaxf(mv3, 0.f)));
}

// ---- output GEMM: [cnt,1408]bf16 @ Wt[128][1408]bf16 + b, relu -> f32 -----
__global__ __launch_bounds__(256) void k_gemm_out(
    const unsigned short* __restrict__ H, const unsigned short* __restrict__ Wt,
    const float* __restrict__ bias, float* __restrict__ out, int Nloc) {
  __shared__ unsigned short Ab[2][64 * 64];     //  8 KB x2
  __shared__ unsigned short Bb[2][128 * 64];    // 16 KB x2
  const int tid = threadIdx.x;
  const int l = tid & 63;
  const int lr = l & 15, lg = l >> 4;
  const int w = tid >> 6, wr = w >> 1, wc = w & 1;
  const int r0 = blockIdx.x * 64;
  const int wbase = tid & 192;                  // w*64, wave-uniform

  f32x4 acc[2][4];
#pragma unroll
  for (int m = 0; m < 2; ++m)
#pragma unroll
    for (int t = 0; t < 4; ++t) {
      f32x4 z = {0.f, 0.f, 0.f, 0.f};
      acc[m][t] = z;
    }

  auto stage = [&](int b, int kb) {
#pragma unroll
    for (int i = 0; i < 2; ++i) {               // A: 64 rows x 8 chunks
      int g = i * 256 + tid;
      int row = g >> 3, c = g & 7;
      int sc = c ^ (row & 7);
      GLD16(H + (size_t)(r0 + row) * 1408 + kb + sc * 8,
            &Ab[b][(size_t)(i * 256 + wbase) * 8]);
    }
#pragma unroll
    for (int i = 0; i < 4; ++i) {               // B: 128 rows x 8 chunks
      int g = i * 256 + tid;
      int row = g >> 3, c = g & 7;
      int sc = c ^ (row & 7);
      GLD16(Wt + (size_t)row * 1408 + kb + sc * 8,
            &Bb[b][(size_t)(i * 256 + wbase) * 8]);
    }
  };

  auto compute = [&](int b) {
#pragma unroll
    for (int kk = 0; kk < 2; ++kk) {
      int chq = kk * 4 + lg;
      bf16x8 a[2], bt[4];
#pragma unroll
      for (int m = 0; m < 2; ++m) {
        int row = wr * 32 + m * 16 + lr;
        a[m] = *(const bf16x8*)&Ab[b][(row * 8 + (chq ^ (row & 7))) * 8];
      }
#pragma unroll
      for (int t = 0; t < 4; ++t) {
        int row = wc * 64 + t * 16 + lr;
        bt[t] = *(const bf16x8*)&Bb[b][(row * 8 + (chq ^ (row & 7))) * 8];
      }
#pragma unroll
      for (int m = 0; m < 2; ++m)
#pragma unroll
        for (int t = 0; t < 4; ++t)
          acc[m][t] = __builtin_amdgcn_mfma_f32_16x16x32_bf16(
              a[m], bt[t], acc[m][t], 0, 0, 0);
    }
  };

  stage(0, 0);
  __syncthreads();
  int cur = 0;
  for (int t = 0; t < 22; ++t) {                // 22 * 64 = K = 1408
    if (t < 21) stage(cur ^ 1, (t + 1) * 64);
    compute(cur);
    __syncthreads();
    cur ^= 1;
  }

#pragma unroll
  for (int m = 0; m < 2; ++m) {
    int rb = r0 + wr * 32 + m * 16 + lg * 4;    // C/D: col=lane&15, row=lg*4+reg
#pragma unroll
    for (int t = 0; t < 4; ++t) {
      int c = wc * 64 + t * 16 + lr;
      float bbias = bias[c];
#pragma unroll
      for (int r = 0; r < 4; ++r) {
        int rr = rb + r;
        if (rr < Nloc) out[(size_t)rr * 128 + c] = fmaxf(acc[m][t][r] + bbias, 0.f);
      }
    }
  }
}

extern "C" void kernel_launch(void* const* d_in, const int* in_sizes, int n_in,
                              void* d_out, int out_size, void* d_ws,
                              size_t ws_size, hipStream_t stream) {
  const float* x_i  = (const float*)d_in[0];
  const float* x_m  = (const float*)d_in[1];
  const int*   ei   = (const int*)d_in[2];
  const float* Wi_i = (const float*)d_in[3];
  const float* bi_i = (const float*)d_in[4];
  const float* Wi_m = (const float*)d_in[5];
  const float* bi_m = (const float*)d_in[6];
  const float* Wsc  = (const float*)d_in[7];
  const float* bsc  = (const float*)d_in[8];
  const float* Wo_i = (const float*)d_in[9];
  const float* bo_i = (const float*)d_in[10];
  const float* Wo_m = (const float*)d_in[11];
  const float* bo_m = (const float*)d_in[12];
  float* out = (float*)d_out;

  int Ni = in_sizes[0] / 128, Nm = in_sizes[1] / 128, E = in_sizes[2] / 2;
  const int* es = ei;
  const int* ee = ei + E;

  char* p = (char*)d_ws;
  auto alloc = [&](size_t bytes) {
    char* q = p;
    p += (bytes + 255) & ~(size_t)255;
    return q;
  };
  unsigned short* xp_i = (unsigned short*)alloc((size_t)Ni * 256 * 2);
  unsigned short* xp_m = (unsigned short*)alloc((size_t)Nm * 256 * 2);
  float* a_i   = (float*)alloc((size_t)Ni * 4);
  float* a_m   = (float*)alloc((size_t)Nm * 4);
  int* deg_i   = (int*)alloc((size_t)Ni * 4);
  int* deg_m   = (int*)alloc((size_t)Nm * 4);
  int* rp_i    = (int*)alloc((size_t)(Ni + 1) * 4);
  int* rp_m    = (int*)alloc((size_t)(Nm + 1) * 4);
  int* cur_i   = (int*)alloc((size_t)Ni * 4);
  int* cur_m   = (int*)alloc((size_t)Nm * 4);
  int* col_i   = (int*)alloc((size_t)E * 4);
  int* col_m   = (int*)alloc((size_t)E * 4);
  float* sv_i  = (float*)alloc((size_t)E * 4);
  float* sv_m  = (float*)alloc((size_t)E * 4);
  unsigned short* Wt_i = (unsigned short*)alloc((size_t)128 * 1408 * 2);
  unsigned short* Wt_m = (unsigned short*)alloc((size_t)128 * 1408 * 2);
  unsigned short* Wint_i = (unsigned short*)alloc((size_t)256 * 128 * 2);
  unsigned short* Wint_m = (unsigned short*)alloc((size_t)256 * 128 * 2);

  size_t used = (size_t)(p - (char*)d_ws);
  if (used + 256 > ws_size) return;
  size_t avail = ws_size - used - 256;
  long long srows_ll = (long long)(avail / (1408 * 2));
  int maxN = (Ni > Nm ? Ni : Nm);
  int maxPad = (maxN + 127) & ~127;
  int S = (int)(srows_ll > maxPad ? maxPad : srows_ll);
  S &= ~127;
  if (S < 128) return;
  unsigned short* Hs = (unsigned short*)alloc((size_t)S * 1408 * 2);

  hipMemsetAsync(deg_i, 0, (size_t)Ni * 4, stream);
  hipMemsetAsync(deg_m, 0, (size_t)Nm * 4, stream);
  hipMemsetAsync(a_i, 0, (size_t)Ni * 4, stream);
  hipMemsetAsync(a_m, 0, (size_t)Nm * 4, stream);

  k_prep_wt<<<(1408 * 128 + 255) / 256, 256, 0, stream>>>(Wo_i, Wt_i, 1408, 128);
  k_prep_wt<<<(1408 * 128 + 255) / 256, 256, 0, stream>>>(Wo_m, Wt_m, 1408, 128);
  k_prep_wt<<<(128 * 256 + 255) / 256, 256, 0, stream>>>(Wi_i, Wint_i, 128, 256);
  k_prep_wt<<<(128 * 256 + 255) / 256, 256, 0, stream>>>(Wi_m, Wint_m, 128, 256);

  k_gemm_in<<<(Ni + 63) / 64, 256, 0, stream>>>(x_i, Wint_i, bi_i, Wsc, xp_i, a_i, Ni);
  k_gemm_in<<<(Nm + 63) / 64, 256, 0, stream>>>(x_m, Wint_m, bi_m, Wsc + 256, xp_m, a_m, Nm);

  k_deg<<<(E + 255) / 256, 256, 0, stream>>>(es, ee, E, deg_i, deg_m);
  k_scan<<<2, 1024, 0, stream>>>(deg_i, rp_i, cur_i, deg_m, rp_m, cur_m, Ni, Nm);
  k_fill<<<(E + 255) / 256, 256, 0, stream>>>(es, ee, E, a_i, a_m, bsc,
                                              cur_i, col_i, sv_i,
                                              cur_m, col_m, sv_m);

  // intt side: own half of pooled cols at [0,256), gathered (mvtx) at [256,512)
  for (int base = 0; base < Ni; base += S) {
    int cnt = Ni - base; if (cnt > S) cnt = S;
    k_agg<<<(cnt + 3) / 4, 256, 0, stream>>>(x_i, xp_i, xp_m, rp_i, col_i,
                                             sv_i, Hs, base, cnt, 0, 256);
    k_gemm_out<<<(cnt + 63) / 64, 256, 0, stream>>>(Hs, Wt_i, bo_i,
                                                    out + (size_t)base * 128, cnt);
  }
  // mvtx side: gathered (intt) at [0,256), own half at [256,512)
  float* out_m = out + (size_t)Ni * 128;
  for (int base = 0; base < Nm; base += S) {
    int cnt = Nm - base; if (cnt > S) cnt = S;
    k_agg<<<(cnt + 3) / 4, 256, 0, stream>>>(x_m, xp_m, xp_i, rp_m, col_m,
                                             sv_m, Hs, base, cnt, 256, 0);
    k_gemm_out<<<(cnt + 63) / 64, 256, 0, stream>>>(Hs, Wt_m, bo_m,
                                                    out_m + (size_t)base * 128, cnt);
  }
}

// Round 11
// 349.881 us; speedup vs baseline: 1.6185x; 1.2589x over previous
//
#include <hip/hip_runtime.h>

// ---------------------------------------------------------------------------
// BipartiteLayer: xp = x@W_in+b ; s = exp(-|[xp_i[s],xp_m[e]]@W_score+b|) ;
// scatter mean/max of xp_pair*s ; h = relu([x,xp,mean,max]@W_out+b)
//
// R11: R10 split pipeline, with the 112-us 2-block serial k_scan replaced by
// a deterministic 3-phase parallel scan (blk-reduce -> top-scan -> blk-write).
// Same ordered CSR bytes -> downstream kernels byte-identical.
//
// Pipeline (slab-chunked H to fit adaptive workspace):
//   k_prep_wt     : W (f32, KxN) -> Wt (N rows x K, bf16) transpose
//   k_gemm_in     : MFMA bf16 K=128 one-shot; fused bias, xp store, a=xp.Ws
//   k_deg / k_scan_blk / k_scan_top / k_scan_wr / k_fill : sorted CSR build
//   per slab:
//     k_agg       : wave-per-node CSR gather-reduce -> H slab rows (1408 bf16)
//     k_gemm_out  : bf16 MFMA, 64x128 tile, BK=64 dbuf LDS via global_load_lds
// ---------------------------------------------------------------------------

typedef __attribute__((ext_vector_type(8))) short bf16x8;   // 8 bf16 = 4 VGPR
typedef __attribute__((ext_vector_type(4))) float f32x4;

static __device__ __forceinline__ unsigned short f2bf(float f) {
  unsigned int u = __float_as_uint(f);
  u = (u + 0x7FFFu + ((u >> 16) & 1u)) >> 16;   // RNE
  return (unsigned short)u;
}
static __device__ __forceinline__ float bf2f(unsigned short s) {
  return __uint_as_float(((unsigned int)s) << 16);
}

#define GLD16(gp, lp)                                                        \
  __builtin_amdgcn_global_load_lds(                                          \
      (const __attribute__((address_space(1))) void*)(gp),                   \
      (__attribute__((address_space(3))) void*)(lp), 16, 0, 0)

// ---- transpose W (KxNcol f32) -> Wt[col][k] bf16 ---------------------------
__global__ void k_prep_wt(const float* __restrict__ Wo,
                          unsigned short* __restrict__ Wt, int K, int Ncol) {
  int idx = blockIdx.x * blockDim.x + threadIdx.x;
  if (idx >= K * Ncol) return;
  int k = idx / Ncol, c = idx % Ncol;
  Wt[(size_t)c * K + k] = f2bf(Wo[idx]);
}

// ---- input GEMM (MFMA): [N,128]f32 @ [128,256] -> xp bf16, a=xp.Ws --------
__global__ __launch_bounds__(256) void k_gemm_in(
    const float* __restrict__ x, const unsigned short* __restrict__ Wint,
    const float* __restrict__ bias, const float* __restrict__ Wsc,
    unsigned short* __restrict__ xp, float* __restrict__ a_out, int N) {
  __shared__ __align__(16) unsigned short Ab[64 * 16 * 8];    // 16 KB
  __shared__ __align__(16) unsigned short Bb[256 * 16 * 8];   // 64 KB
  const int tid = threadIdx.x;
  const int l = tid & 63;
  const int lr = l & 15, lg = l >> 4;
  const int w = tid >> 6, wr = w >> 1, wc = w & 1;
  const int r0 = blockIdx.x * 64;
  const int wbase = tid & 192;                  // w*64, wave-uniform

#pragma unroll
  for (int i = 0; i < 16; ++i) {                // B: 256 rows x 16 chunks
    int g = i * 256 + tid;
    int row = g >> 4, c = g & 15;
    int sc = c ^ (row & 7);
    GLD16(Wint + (size_t)row * 128 + sc * 8,
          &Bb[(size_t)(i * 256 + wbase) * 8]);
  }
#pragma unroll
  for (int i = 0; i < 4; ++i) {                 // A: reg-stage f32->bf16
    int g = i * 256 + tid;
    int row = g >> 4, c = g & 15;
    int ar = min(r0 + row, N - 1);
    const float* src = x + (size_t)ar * 128 + c * 8;
    float4 u = *(const float4*)src;
    float4 v = *(const float4*)(src + 4);
    bf16x8 h;
    h[0] = (short)f2bf(u.x); h[1] = (short)f2bf(u.y);
    h[2] = (short)f2bf(u.z); h[3] = (short)f2bf(u.w);
    h[4] = (short)f2bf(v.x); h[5] = (short)f2bf(v.y);
    h[6] = (short)f2bf(v.z); h[7] = (short)f2bf(v.w);
    *(bf16x8*)&Ab[(size_t)(row * 16 + (c ^ (row & 7))) * 8] = h;
  }
  __syncthreads();

  f32x4 acc[2][8];
#pragma unroll
  for (int m = 0; m < 2; ++m)
#pragma unroll
    for (int t = 0; t < 8; ++t) {
      f32x4 z = {0.f, 0.f, 0.f, 0.f};
      acc[m][t] = z;
    }
#pragma unroll
  for (int kk = 0; kk < 4; ++kk) {
    int chq = kk * 4 + lg;
    bf16x8 a[2], bt[8];
#pragma unroll
    for (int m = 0; m < 2; ++m) {
      int row = wr * 32 + m * 16 + lr;
      a[m] = *(const bf16x8*)&Ab[(row * 16 + (chq ^ (row & 7))) * 8];
    }
#pragma unroll
    for (int t = 0; t < 8; ++t) {
      int row = wc * 128 + t * 16 + lr;
      bt[t] = *(const bf16x8*)&Bb[(row * 16 + (chq ^ (row & 7))) * 8];
    }
#pragma unroll
    for (int m = 0; m < 2; ++m)
#pragma unroll
      for (int t = 0; t < 8; ++t)
        acc[m][t] = __builtin_amdgcn_mfma_f32_16x16x32_bf16(
            a[m], bt[t], acc[m][t], 0, 0, 0);
  }

  float wscv[8], bb[8];
#pragma unroll
  for (int t = 0; t < 8; ++t) {
    int c = wc * 128 + t * 16 + lr;
    wscv[t] = Wsc[c];
    bb[t] = bias[c];
  }
#pragma unroll
  for (int m = 0; m < 2; ++m) {
    int rb = r0 + wr * 32 + m * 16 + lg * 4;    // C/D: col=lane&15, row=lg*4+reg
    float p0 = 0.f, p1 = 0.f, p2 = 0.f, p3 = 0.f;
#pragma unroll
    for (int t = 0; t < 8; ++t) {
      int c = wc * 128 + t * 16 + lr;
      float v0 = acc[m][t][0] + bb[t];
      float v1 = acc[m][t][1] + bb[t];
      float v2 = acc[m][t][2] + bb[t];
      float v3 = acc[m][t][3] + bb[t];
      if (rb + 0 < N) xp[(size_t)(rb + 0) * 256 + c] = f2bf(v0);
      if (rb + 1 < N) xp[(size_t)(rb + 1) * 256 + c] = f2bf(v1);
      if (rb + 2 < N) xp[(size_t)(rb + 2) * 256 + c] = f2bf(v2);
      if (rb + 3 < N) xp[(size_t)(rb + 3) * 256 + c] = f2bf(v3);
      p0 = fmaf(v0, wscv[t], p0); p1 = fmaf(v1, wscv[t], p1);
      p2 = fmaf(v2, wscv[t], p2); p3 = fmaf(v3, wscv[t], p3);
    }
#pragma unroll
    for (int off = 1; off < 16; off <<= 1) {
      p0 += __shfl_xor(p0, off); p1 += __shfl_xor(p1, off);
      p2 += __shfl_xor(p2, off); p3 += __shfl_xor(p3, off);
    }
    if (lr == 0) {
      if (rb + 0 < N) atomicAdd(a_out + rb + 0, p0);
      if (rb + 1 < N) atomicAdd(a_out + rb + 1, p1);
      if (rb + 2 < N) atomicAdd(a_out + rb + 2, p2);
      if (rb + 3 < N) atomicAdd(a_out + rb + 3, p3);
    }
  }
}

// ---- CSR build: degree histogram ------------------------------------------
__global__ void k_deg(const int* __restrict__ es, const int* __restrict__ ee,
                      int E, int* __restrict__ deg_i, int* __restrict__ deg_m) {
  int e = blockIdx.x * blockDim.x + threadIdx.x;
  if (e >= E) return;
  atomicAdd(deg_i + es[e], 1);
  atomicAdd(deg_m + ee[e], 1);
}

// ---- CSR scan phase 1: per-block (256 nodes) degree sum --------------------
__global__ __launch_bounds__(256) void k_scan_blk(
    const int* __restrict__ deg, int* __restrict__ blksum, int n) {
  __shared__ int sm[256];
  int t = threadIdx.x;
  int i = blockIdx.x * 256 + t;
  sm[t] = (i < n) ? deg[i] : 0;
  __syncthreads();
#pragma unroll
  for (int off = 128; off; off >>= 1) {
    if (t < off) sm[t] += sm[t + off];
    __syncthreads();
  }
  if (t == 0) blksum[blockIdx.x] = sm[0];
}

// ---- CSR scan phase 2: exclusive scan of block sums (<=1024 blocks/side) --
__global__ __launch_bounds__(1024) void k_scan_top(
    const int* __restrict__ bs_i, int* __restrict__ bb_i, int nbi,
    const int* __restrict__ bs_m, int* __restrict__ bb_m, int nbm) {
  const int* bs = blockIdx.x ? bs_m : bs_i;
  int* bb = blockIdx.x ? bb_m : bb_i;
  int nb = blockIdx.x ? nbm : nbi;
  __shared__ int sm[1024];
  int t = threadIdx.x;
  int d = (t < nb) ? bs[t] : 0;
  sm[t] = d;
  __syncthreads();
  for (int off = 1; off < 1024; off <<= 1) {    // Hillis-Steele inclusive
    int v = (t >= off) ? sm[t - off] : 0;
    __syncthreads();
    sm[t] += v;
    __syncthreads();
  }
  if (t < nb) bb[t] = sm[t] - d;                // exclusive
}

// ---- CSR scan phase 3: per-block exclusive scan + base -> rp, cur ---------
__global__ __launch_bounds__(256) void k_scan_wr(
    const int* __restrict__ deg, const int* __restrict__ blkbase,
    int* __restrict__ rp, int* __restrict__ cur, int n, int E) {
  __shared__ int sm[256];
  int t = threadIdx.x;
  int i = blockIdx.x * 256 + t;
  int d = (i < n) ? deg[i] : 0;
  sm[t] = d;
  __syncthreads();
  for (int off = 1; off < 256; off <<= 1) {     // Hillis-Steele inclusive
    int v = (t >= off) ? sm[t - off] : 0;
    __syncthreads();
    sm[t] += v;
    __syncthreads();
  }
  if (i < n) {
    int v = blkbase[blockIdx.x] + sm[t] - d;    // exclusive + block base
    rp[i] = v; cur[i] = v;
  }
  if (i == 0) rp[n] = E;
}

// ---- CSR build: score + fill ----------------------------------------------
__global__ void k_fill(const int* __restrict__ es, const int* __restrict__ ee,
                       int E, const float* __restrict__ a_i,
                       const float* __restrict__ a_m,
                       const float* __restrict__ bsc,
                       int* __restrict__ cur_i, int* __restrict__ col_i,
                       float* __restrict__ sv_i,
                       int* __restrict__ cur_m, int* __restrict__ col_m,
                       float* __restrict__ sv_m) {
  int e = blockIdx.x * blockDim.x + threadIdx.x;
  if (e >= E) return;
  int s = es[e], m = ee[e];
  float sc = expf(-fabsf(a_i[s] + a_m[m] + bsc[0]));
  int pi = atomicAdd(cur_i + s, 1);
  col_i[pi] = m; sv_i[pi] = sc;
  int pm = atomicAdd(cur_m + m, 1);
  col_m[pm] = s; sv_m[pm] = sc;
}

// ---- wave-per-node CSR aggregation -> H slab row (1408 bf16) ---------------
// H = [x(128) | xp(256) | mean(512) | max(512)]; 4 gathers in flight.
__global__ __launch_bounds__(256) void k_agg(
    const float* __restrict__ x_own, const unsigned short* __restrict__ xp_own,
    const unsigned short* __restrict__ xp_oth,
    const int* __restrict__ rowptr, const int* __restrict__ col,
    const float* __restrict__ sv, unsigned short* __restrict__ H,
    int base, int cnt, int own_off, int oth_off) {
  int local = blockIdx.x * 4 + (threadIdx.x >> 6);
  if (local >= cnt) return;                      // wave-uniform
  int node = base + local;
  int l = threadIdx.x & 63;
  ushort4 xo = *(const ushort4*)(xp_own + (size_t)node * 256 + 4 * l);
  float xp0 = bf2f(xo.x), xp1 = bf2f(xo.y), xp2 = bf2f(xo.z), xp3 = bf2f(xo.w);
  float2 xv = *(const float2*)(x_own + (size_t)node * 128 + 2 * l);
  unsigned short* Hr = H + (size_t)local * 1408;
  *(ushort2*)(Hr + 2 * l) = make_ushort2(f2bf(xv.x), f2bf(xv.y));
  *(ushort4*)(Hr + 128 + 4 * l) = xo;

  float sum_s = 0.f, mx_s = -1e30f, mn_s = 1e30f;
  float sv0 = 0.f, sv1 = 0.f, sv2 = 0.f, sv3 = 0.f;
  float mv0 = -1e30f, mv1 = -1e30f, mv2 = -1e30f, mv3 = -1e30f;
  int jb = rowptr[node], je = rowptr[node + 1];
  int dg = je - jb;
  int j = jb;
  for (; j + 3 < je; j += 4) {                   // 4 independent gathers
    int o0 = col[j], o1 = col[j + 1], o2 = col[j + 2], o3 = col[j + 3];
    float s0 = sv[j], s1 = sv[j + 1], s2 = sv[j + 2], s3 = sv[j + 3];
    ushort4 g0 = *(const ushort4*)(xp_oth + (size_t)o0 * 256 + 4 * l);
    ushort4 g1 = *(const ushort4*)(xp_oth + (size_t)o1 * 256 + 4 * l);
    ushort4 g2 = *(const ushort4*)(xp_oth + (size_t)o2 * 256 + 4 * l);
    ushort4 g3 = *(const ushort4*)(xp_oth + (size_t)o3 * 256 + 4 * l);
    float f0, f1, f2, f3;
    f0 = bf2f(g0.x); f1 = bf2f(g0.y); f2 = bf2f(g0.z); f3 = bf2f(g0.w);
    sv0 = fmaf(s0, f0, sv0); sv1 = fmaf(s0, f1, sv1);
    sv2 = fmaf(s0, f2, sv2); sv3 = fmaf(s0, f3, sv3);
    mv0 = fmaxf(mv0, s0 * f0); mv1 = fmaxf(mv1, s0 * f1);
    mv2 = fmaxf(mv2, s0 * f2); mv3 = fmaxf(mv3, s0 * f3);
    f0 = bf2f(g1.x); f1 = bf2f(g1.y); f2 = bf2f(g1.z); f3 = bf2f(g1.w);
    sv0 = fmaf(s1, f0, sv0); sv1 = fmaf(s1, f1, sv1);
    sv2 = fmaf(s1, f2, sv2); sv3 = fmaf(s1, f3, sv3);
    mv0 = fmaxf(mv0, s1 * f0); mv1 = fmaxf(mv1, s1 * f1);
    mv2 = fmaxf(mv2, s1 * f2); mv3 = fmaxf(mv3, s1 * f3);
    f0 = bf2f(g2.x); f1 = bf2f(g2.y); f2 = bf2f(g2.z); f3 = bf2f(g2.w);
    sv0 = fmaf(s2, f0, sv0); sv1 = fmaf(s2, f1, sv1);
    sv2 = fmaf(s2, f2, sv2); sv3 = fmaf(s2, f3, sv3);
    mv0 = fmaxf(mv0, s2 * f0); mv1 = fmaxf(mv1, s2 * f1);
    mv2 = fmaxf(mv2, s2 * f2); mv3 = fmaxf(mv3, s2 * f3);
    f0 = bf2f(g3.x); f1 = bf2f(g3.y); f2 = bf2f(g3.z); f3 = bf2f(g3.w);
    sv0 = fmaf(s3, f0, sv0); sv1 = fmaf(s3, f1, sv1);
    sv2 = fmaf(s3, f2, sv2); sv3 = fmaf(s3, f3, sv3);
    mv0 = fmaxf(mv0, s3 * f0); mv1 = fmaxf(mv1, s3 * f1);
    mv2 = fmaxf(mv2, s3 * f2); mv3 = fmaxf(mv3, s3 * f3);
    sum_s += (s0 + s1) + (s2 + s3);
    mx_s = fmaxf(mx_s, fmaxf(fmaxf(s0, s1), fmaxf(s2, s3)));
    mn_s = fminf(mn_s, fminf(fminf(s0, s1), fminf(s2, s3)));
  }
  for (; j < je; ++j) {                          // tail 0..3
    int o0 = col[j];
    float s0 = sv[j];
    ushort4 g0 = *(const ushort4*)(xp_oth + (size_t)o0 * 256 + 4 * l);
    float f0 = bf2f(g0.x), f1 = bf2f(g0.y), f2 = bf2f(g0.z), f3 = bf2f(g0.w);
    sv0 = fmaf(s0, f0, sv0); sv1 = fmaf(s0, f1, sv1);
    sv2 = fmaf(s0, f2, sv2); sv3 = fmaf(s0, f3, sv3);
    mv0 = fmaxf(mv0, s0 * f0); mv1 = fmaxf(mv1, s0 * f1);
    mv2 = fmaxf(mv2, s0 * f2); mv3 = fmaxf(mv3, s0 * f3);
    sum_s += s0; mx_s = fmaxf(mx_s, s0); mn_s = fminf(mn_s, s0);
  }
  float inv = 1.f / (float)(dg > 0 ? dg : 1);
  float ss = sum_s * inv;
  *(ushort4*)(Hr + 384 + own_off + 4 * l) = make_ushort4(
      f2bf(xp0 * ss), f2bf(xp1 * ss), f2bf(xp2 * ss), f2bf(xp3 * ss));
  *(ushort4*)(Hr + 384 + oth_off + 4 * l) = make_ushort4(
      f2bf(sv0 * inv), f2bf(sv1 * inv), f2bf(sv2 * inv), f2bf(sv3 * inv));
  float a0, a1, a2, a3;
  if (dg > 0) {
    a0 = fmaxf(fmaxf(xp0 * mx_s, xp0 * mn_s), 0.f);
    a1 = fmaxf(fmaxf(xp1 * mx_s, xp1 * mn_s), 0.f);
    a2 = fmaxf(fmaxf(xp2 * mx_s, xp2 * mn_s), 0.f);
    a3 = fmaxf(fmaxf(xp3 * mx_s, xp3 * mn_s), 0.f);
  } else {
    a0 = a1 = a2 = a3 = 0.f;
  }
  *(ushort4*)(Hr + 896 + own_off + 4 * l) =
      make_ushort4(f2bf(a0), f2bf(a1), f2bf(a2), f2bf(a3));
  *(ushort4*)(Hr + 896 + oth_off + 4 * l) =
      make_ushort4(f2bf(fmaxf(mv0, 0.f)), f2bf(fmaxf(mv1, 0.f)),
                   f2bf(fmaxf(mv2, 0.f)), f2bf(fmaxf(mv3, 0.f)));
}

// ---- output GEMM: [cnt,1408]bf16 @ Wt[128][1408]bf16 + b, relu -> f32 -----
__global__ __launch_bounds__(256) void k_gemm_out(
    const unsigned short* __restrict__ H, const unsigned short* __restrict__ Wt,
    const float* __restrict__ bias, float* __restrict__ out, int Nloc) {
  __shared__ unsigned short Ab[2][64 * 64];     //  8 KB x2
  __shared__ unsigned short Bb[2][128 * 64];    // 16 KB x2
  const int tid = threadIdx.x;
  const int l = tid & 63;
  const int lr = l & 15, lg = l >> 4;
  const int w = tid >> 6, wr = w >> 1, wc = w & 1;
  const int r0 = blockIdx.x * 64;
  const int wbase = tid & 192;                  // w*64, wave-uniform

  f32x4 acc[2][4];
#pragma unroll
  for (int m = 0; m < 2; ++m)
#pragma unroll
    for (int t = 0; t < 4; ++t) {
      f32x4 z = {0.f, 0.f, 0.f, 0.f};
      acc[m][t] = z;
    }

  auto stage = [&](int b, int kb) {
#pragma unroll
    for (int i = 0; i < 2; ++i) {               // A: 64 rows x 8 chunks
      int g = i * 256 + tid;
      int row = g >> 3, c = g & 7;
      int sc = c ^ (row & 7);
      GLD16(H + (size_t)(r0 + row) * 1408 + kb + sc * 8,
            &Ab[b][(size_t)(i * 256 + wbase) * 8]);
    }
#pragma unroll
    for (int i = 0; i < 4; ++i) {               // B: 128 rows x 8 chunks
      int g = i * 256 + tid;
      int row = g >> 3, c = g & 7;
      int sc = c ^ (row & 7);
      GLD16(Wt + (size_t)row * 1408 + kb + sc * 8,
            &Bb[b][(size_t)(i * 256 + wbase) * 8]);
    }
  };

  auto compute = [&](int b) {
#pragma unroll
    for (int kk = 0; kk < 2; ++kk) {
      int chq = kk * 4 + lg;
      bf16x8 a[2], bt[4];
#pragma unroll
      for (int m = 0; m < 2; ++m) {
        int row = wr * 32 + m * 16 + lr;
        a[m] = *(const bf16x8*)&Ab[b][(row * 8 + (chq ^ (row & 7))) * 8];
      }
#pragma unroll
      for (int t = 0; t < 4; ++t) {
        int row = wc * 64 + t * 16 + lr;
        bt[t] = *(const bf16x8*)&Bb[b][(row * 8 + (chq ^ (row & 7))) * 8];
      }
#pragma unroll
      for (int m = 0; m < 2; ++m)
#pragma unroll
        for (int t = 0; t < 4; ++t)
          acc[m][t] = __builtin_amdgcn_mfma_f32_16x16x32_bf16(
              a[m], bt[t], acc[m][t], 0, 0, 0);
    }
  };

  stage(0, 0);
  __syncthreads();
  int cur = 0;
  for (int t = 0; t < 22; ++t) {                // 22 * 64 = K = 1408
    if (t < 21) stage(cur ^ 1, (t + 1) * 64);
    compute(cur);
    __syncthreads();
    cur ^= 1;
  }

#pragma unroll
  for (int m = 0; m < 2; ++m) {
    int rb = r0 + wr * 32 + m * 16 + lg * 4;    // C/D: col=lane&15, row=lg*4+reg
#pragma unroll
    for (int t = 0; t < 4; ++t) {
      int c = wc * 64 + t * 16 + lr;
      float bbias = bias[c];
#pragma unroll
      for (int r = 0; r < 4; ++r) {
        int rr = rb + r;
        if (rr < Nloc) out[(size_t)rr * 128 + c] = fmaxf(acc[m][t][r] + bbias, 0.f);
      }
    }
  }
}

extern "C" void kernel_launch(void* const* d_in, const int* in_sizes, int n_in,
                              void* d_out, int out_size, void* d_ws,
                              size_t ws_size, hipStream_t stream) {
  const float* x_i  = (const float*)d_in[0];
  const float* x_m  = (const float*)d_in[1];
  const int*   ei   = (const int*)d_in[2];
  const float* Wi_i = (const float*)d_in[3];
  const float* bi_i = (const float*)d_in[4];
  const float* Wi_m = (const float*)d_in[5];
  const float* bi_m = (const float*)d_in[6];
  const float* Wsc  = (const float*)d_in[7];
  const float* bsc  = (const float*)d_in[8];
  const float* Wo_i = (const float*)d_in[9];
  const float* bo_i = (const float*)d_in[10];
  const float* Wo_m = (const float*)d_in[11];
  const float* bo_m = (const float*)d_in[12];
  float* out = (float*)d_out;

  int Ni = in_sizes[0] / 128, Nm = in_sizes[1] / 128, E = in_sizes[2] / 2;
  const int* es = ei;
  const int* ee = ei + E;
  int nbi = (Ni + 255) / 256, nbm = (Nm + 255) / 256;   // <= 1024 assumed

  char* p = (char*)d_ws;
  auto alloc = [&](size_t bytes) {
    char* q = p;
    p += (bytes + 255) & ~(size_t)255;
    return q;
  };
  unsigned short* xp_i = (unsigned short*)alloc((size_t)Ni * 256 * 2);
  unsigned short* xp_m = (unsigned short*)alloc((size_t)Nm * 256 * 2);
  float* a_i   = (float*)alloc((size_t)Ni * 4);
  float* a_m   = (float*)alloc((size_t)Nm * 4);
  int* deg_i   = (int*)alloc((size_t)Ni * 4);
  int* deg_m   = (int*)alloc((size_t)Nm * 4);
  int* rp_i    = (int*)alloc((size_t)(Ni + 1) * 4);
  int* rp_m    = (int*)alloc((size_t)(Nm + 1) * 4);
  int* cur_i   = (int*)alloc((size_t)Ni * 4);
  int* cur_m   = (int*)alloc((size_t)Nm * 4);
  int* bs_i    = (int*)alloc((size_t)nbi * 4);
  int* bs_m    = (int*)alloc((size_t)nbm * 4);
  int* bb_i    = (int*)alloc((size_t)nbi * 4);
  int* bb_m    = (int*)alloc((size_t)nbm * 4);
  int* col_i   = (int*)alloc((size_t)E * 4);
  int* col_m   = (int*)alloc((size_t)E * 4);
  float* sv_i  = (float*)alloc((size_t)E * 4);
  float* sv_m  = (float*)alloc((size_t)E * 4);
  unsigned short* Wt_i = (unsigned short*)alloc((size_t)128 * 1408 * 2);
  unsigned short* Wt_m = (unsigned short*)alloc((size_t)128 * 1408 * 2);
  unsigned short* Wint_i = (unsigned short*)alloc((size_t)256 * 128 * 2);
  unsigned short* Wint_m = (unsigned short*)alloc((size_t)256 * 128 * 2);

  size_t used = (size_t)(p - (char*)d_ws);
  if (used + 256 > ws_size) return;
  size_t avail = ws_size - used - 256;
  long long srows_ll = (long long)(avail / (1408 * 2));
  int maxN = (Ni > Nm ? Ni : Nm);
  int maxPad = (maxN + 127) & ~127;
  int S = (int)(srows_ll > maxPad ? maxPad : srows_ll);
  S &= ~127;
  if (S < 128) return;
  unsigned short* Hs = (unsigned short*)alloc((size_t)S * 1408 * 2);

  hipMemsetAsync(deg_i, 0, (size_t)Ni * 4, stream);
  hipMemsetAsync(deg_m, 0, (size_t)Nm * 4, stream);
  hipMemsetAsync(a_i, 0, (size_t)Ni * 4, stream);
  hipMemsetAsync(a_m, 0, (size_t)Nm * 4, stream);

  k_prep_wt<<<(1408 * 128 + 255) / 256, 256, 0, stream>>>(Wo_i, Wt_i, 1408, 128);
  k_prep_wt<<<(1408 * 128 + 255) / 256, 256, 0, stream>>>(Wo_m, Wt_m, 1408, 128);
  k_prep_wt<<<(128 * 256 + 255) / 256, 256, 0, stream>>>(Wi_i, Wint_i, 128, 256);
  k_prep_wt<<<(128 * 256 + 255) / 256, 256, 0, stream>>>(Wi_m, Wint_m, 128, 256);

  k_gemm_in<<<(Ni + 63) / 64, 256, 0, stream>>>(x_i, Wint_i, bi_i, Wsc, xp_i, a_i, Ni);
  k_gemm_in<<<(Nm + 63) / 64, 256, 0, stream>>>(x_m, Wint_m, bi_m, Wsc + 256, xp_m, a_m, Nm);

  k_deg<<<(E + 255) / 256, 256, 0, stream>>>(es, ee, E, deg_i, deg_m);
  k_scan_blk<<<nbi, 256, 0, stream>>>(deg_i, bs_i, Ni);
  k_scan_blk<<<nbm, 256, 0, stream>>>(deg_m, bs_m, Nm);
  k_scan_top<<<2, 1024, 0, stream>>>(bs_i, bb_i, nbi, bs_m, bb_m, nbm);
  k_scan_wr<<<nbi, 256, 0, stream>>>(deg_i, bb_i, rp_i, cur_i, Ni, E);
  k_scan_wr<<<nbm, 256, 0, stream>>>(deg_m, bb_m, rp_m, cur_m, Nm, E);
  k_fill<<<(E + 255) / 256, 256, 0, stream>>>(es, ee, E, a_i, a_m, bsc,
                                              cur_i, col_i, sv_i,
                                              cur_m, col_m, sv_m);

  // intt side: own half of pooled cols at [0,256), gathered (mvtx) at [256,512)
  for (int base = 0; base < Ni; base += S) {
    int cnt = Ni - base; if (cnt > S) cnt = S;
    k_agg<<<(cnt + 3) / 4, 256, 0, stream>>>(x_i, xp_i, xp_m, rp_i, col_i,
                                             sv_i, Hs, base, cnt, 0, 256);
    k_gemm_out<<<(cnt + 63) / 64, 256, 0, stream>>>(Hs, Wt_i, bo_i,
                                                    out + (size_t)base * 128, cnt);
  }
  // mvtx side: gathered (intt) at [0,256), own half at [256,512)
  float* out_m = out + (size_t)Ni * 128;
  for (int base = 0; base < Nm; base += S) {
    int cnt = Nm - base; if (cnt > S) cnt = S;
    k_agg<<<(cnt + 3) / 4, 256, 0, stream>>>(x_m, xp_m, xp_i, rp_m, col_m,
                                             sv_m, Hs, base, cnt, 256, 0);
    k_gemm_out<<<(cnt + 63) / 64, 256, 0, stream>>>(Hs, Wt_m, bo_m,
                                                    out_m + (size_t)base * 128, cnt);
  }
}